// Round 7
// baseline (318.823 us; speedup 1.0000x reference)
//
#include <hip/hip_runtime.h>
#include <hip/hip_bf16.h>

// KMeans assign via fp16 coarse MFMA + exact fp32 fixup of near-tie rows.
// argmin_k ||xe - c_k|| == argmin_k ( ||c_k||^2 - 2*xe.c_k ),  xe = x + 1e-6.
// Rows with coarse top2 gap < TAU=0.3 are exactly rescored in fp32.
//
// R5: 256x256 tile + R4's counted-vmcnt skeleton. R4 (verified): counted
// vmcnt + multi-buf gave 127.6->102.7us at 128^2; staging traffic (256KB x
// 4096 blocks = 1GB through L2->LDS) is the remaining tax. 256^2 halves it
// (512KB x 1024). 8 waves/block (512 thr), wave tile 128x64, BK=32,
// A 3-buf + B 2-buf = 80KB LDS, s_waitcnt vmcnt(2) + one s_barrier per
// K-step (vmcnt(0) last step). In-block pipeline covers latency at 1-2
// blocks/CU (R4-proven mechanism, R3's failure was the barrier-drain
// structure not tile size per se).
// Also: memset nodes removed (ctr zeroed in prep; rlist clamped in fixup),
// prep_x+prep_c fused.
// SQ_LDS_BANK_CONFLICT == 8 cyc per global_load_lds DMA instr (fixed cost,
// exact-count verified R1/R2/R3/R4). Predicted here: 4,194,304.

#define EPS 1e-6f
#define TAU 0.3f

constexpr int BROWS = 32768;   // 8*4096 rows
constexpr int DD    = 512;
constexpr int KC    = 2048;    // centroids
constexpr int FCAP  = 4096;    // max flagged rows handled exactly
constexpr int NK    = DD / 32; // 16 K-steps

typedef _Float16 half8  __attribute__((ext_vector_type(8)));
typedef _Float16 half4v __attribute__((ext_vector_type(4)));
typedef float    f32x4  __attribute__((ext_vector_type(4)));

// ---------------- fused prep: x->fp16(+eps), centroids->fp16 + csq ----------
__global__ __launch_bounds__(256) void prep(const float* __restrict__ x,
                                            const float* __restrict__ cen,
                                            _Float16* __restrict__ xh,
                                            _Float16* __restrict__ ch,
                                            float* __restrict__ csq,
                                            int* __restrict__ ctr) {
    const int bid = blockIdx.x;
    if (bid < KC / 4) {
        // centroid block (grid 512 -> 2048 rows)
        if (bid == 0 && threadIdx.x == 0) *ctr = 0;
        int w = threadIdx.x >> 6, lane = threadIdx.x & 63;
        int c = bid * 4 + w;
        const float* row = cen + (size_t)c * DD;
        float4 v0 = *(const float4*)(row + lane * 8);
        float4 v1 = *(const float4*)(row + lane * 8 + 4);
        half8 h;
        h[0] = (_Float16)v0.x; h[1] = (_Float16)v0.y; h[2] = (_Float16)v0.z; h[3] = (_Float16)v0.w;
        h[4] = (_Float16)v1.x; h[5] = (_Float16)v1.y; h[6] = (_Float16)v1.z; h[7] = (_Float16)v1.w;
        *(half8*)(ch + (size_t)c * DD + lane * 8) = h;
        float s = v0.x*v0.x + v0.y*v0.y + v0.z*v0.z + v0.w*v0.w
                + v1.x*v1.x + v1.y*v1.y + v1.z*v1.z + v1.w*v1.w;
        #pragma unroll
        for (int off = 32; off > 0; off >>= 1) s += __shfl_down(s, off, 64);
        if (lane == 0) csq[c] = s;
    } else {
        size_t i = ((size_t)(bid - KC / 4) * 256 + threadIdx.x) * 4;
        float4 v = *(const float4*)(x + i);
        half4v h;
        h[0] = (_Float16)(v.x + EPS); h[1] = (_Float16)(v.y + EPS);
        h[2] = (_Float16)(v.z + EPS); h[3] = (_Float16)(v.w + EPS);
        *(half4v*)(xh + i) = h;
    }
}

// ---------------- coarse fp16 MFMA distance + per-row top2 ------------------
// 256x256 tile, 8 waves (2 row-groups x 4 col-groups), wave tile 128x64.
// A 3-buf (stage k+2), B 2-buf (stage k+1), vmcnt(2)+s_barrier per step.
__global__ __launch_bounds__(512, 2) void dist_f16(const _Float16* __restrict__ xh,
                                                   const _Float16* __restrict__ ch,
                                                   const float* __restrict__ csq,
                                                   float* __restrict__ pbest,
                                                   float* __restrict__ psec,
                                                   int*   __restrict__ pidx) {
    // A bufs: smem + {0,1,2}*8192 halfs; B bufs: smem + 24576 + {0,1}*8192.
    __shared__ __align__(16) _Float16 smem[5 * 8192];     // 80 KB exactly

    const int tid = threadIdx.x;
    const int w = tid >> 6, lane = tid & 63;
    const int wr = w >> 2, wc = w & 3;
    const int quad = lane >> 4, u = lane & 15;
    const int rowBase = blockIdx.x * 256;
    const int colBase = blockIdx.y * 256;

    // csq loads pinned before the pipeline (cannot cross the asm fences).
    float cq[4];
    #pragma unroll
    for (int fc = 0; fc < 4; fc++) cq[fc] = csq[colBase + wc * 64 + fc * 16 + u];

    // Staging granules (16B each), g in [0,1024): LDS row g>>2, slot g&3.
    const int g0 = 128 * w + lane;
    const int g1 = g0 + 64;
    const int r0 = g0 >> 2, h0 = g0 & 3;
    const int r1 = g1 >> 2, h1 = g1 & 3;
    const _Float16* pa0 = xh + (size_t)(rowBase + r0) * DD + h0 * 8;
    const _Float16* pa1 = xh + (size_t)(rowBase + r1) * DD + h1 * 8;
    const _Float16* pb0 = ch + (size_t)(colBase + r0) * DD + h0 * 8;
    const _Float16* pb1 = ch + (size_t)(colBase + r1) * DD + h1 * 8;

    auto stageA = [&](int kt) {   // 2 global_load_lds per thread
        _Float16* dst = smem + (kt % 3) * 8192;
        const int off = kt * 32;
        __builtin_amdgcn_global_load_lds(
            (const __attribute__((address_space(1))) void*)(pa0 + off),
            (__attribute__((address_space(3))) void*)(dst + g0 * 8), 16, 0, 0);
        __builtin_amdgcn_global_load_lds(
            (const __attribute__((address_space(1))) void*)(pa1 + off),
            (__attribute__((address_space(3))) void*)(dst + g1 * 8), 16, 0, 0);
    };
    auto stageB = [&](int kt) {   // 2 global_load_lds per thread
        _Float16* dst = smem + 24576 + (kt % 2) * 8192;
        const int off = kt * 32;
        __builtin_amdgcn_global_load_lds(
            (const __attribute__((address_space(1))) void*)(pb0 + off),
            (__attribute__((address_space(3))) void*)(dst + g0 * 8), 16, 0, 0);
        __builtin_amdgcn_global_load_lds(
            (const __attribute__((address_space(1))) void*)(pb1 + off),
            (__attribute__((address_space(3))) void*)(dst + g1 * 8), 16, 0, 0);
    };

    f32x4 acc[8][4] = {};

    // prologue: queue = [A0, B0, A1] (6 loads/thread outstanding)
    stageA(0); stageB(0); stageA(1);

    for (int kc = 0; kc < NK; kc++) {
        // wait for tiles A(kc), B(kc); leave A(kc+1)'s 2 loads in flight.
        if (kc + 1 < NK) asm volatile("s_waitcnt vmcnt(2)" ::: "memory");
        else             asm volatile("s_waitcnt vmcnt(0)" ::: "memory");
        __builtin_amdgcn_s_barrier();
        asm volatile("" ::: "memory");
        __builtin_amdgcn_sched_barrier(0);

        if (kc + 1 < NK) stageB(kc + 1);   // into bbuf[(kc+1)%2] (reads of kc-1 retired)
        if (kc + 2 < NK) stageA(kc + 2);   // into abuf[(kc+2)%3] (reads of kc-1 retired)

        const _Float16* abuf = smem + (kc % 3) * 8192;
        const _Float16* bbuf = smem + 24576 + (kc % 2) * 8192;
        half8 af[8], bf[4];
        #pragma unroll
        for (int f = 0; f < 8; f++)
            af[f] = *(const half8*)(abuf + (wr * 128 + f * 16 + u) * 32 + quad * 8);
        #pragma unroll
        for (int f = 0; f < 4; f++)
            bf[f] = *(const half8*)(bbuf + (wc * 64 + f * 16 + u) * 32 + quad * 8);

        #pragma unroll
        for (int fr = 0; fr < 8; fr++)
            #pragma unroll
            for (int fc = 0; fc < 4; fc++)
                acc[fr][fc] = __builtin_amdgcn_mfma_f32_16x16x32_f16(af[fr], bf[fc], acc[fr][fc], 0, 0, 0);
    }

    __syncthreads();   // all LDS reads retired; safe to overlay epilogue staging

    // epilogue staging overlays the A-buffers (12 KB of 80 KB).
    float* ebf = (float*)smem;           // [8][128]
    float* esf = ebf + 8 * 128;          // [8][128]
    int*   eif = (int*)(esf + 8 * 128);  // [8][128]

    const int cbi = blockIdx.y * 4 + wc;
    const int colQuadBase = colBase + wc * 64;

    #pragma unroll
    for (int fr = 0; fr < 8; fr++) {
        #pragma unroll
        for (int reg = 0; reg < 4; reg++) {
            float vv[4];
            #pragma unroll
            for (int fc = 0; fc < 4; fc++) vv[fc] = cq[fc] - 2.0f * acc[fr][fc][reg];
            // top2 of 4 (min/max network); no coarse tie-break needed
            float mn01 = fminf(vv[0], vv[1]), mx01 = fmaxf(vv[0], vv[1]);
            float mn23 = fminf(vv[2], vv[3]), mx23 = fmaxf(vv[2], vv[3]);
            float b = fminf(mn01, mn23);
            float s = fminf(fmaxf(mn01, mn23), fminf(mx01, mx23));
            #pragma unroll
            for (int m = 1; m < 16; m <<= 1) {   // butterfly within quad
                float ob = __shfl_xor(b, m, 64);
                float os = __shfl_xor(s, m, 64);
                s = fminf(fminf(s, os), fmaxf(b, ob));
                b = fminf(b, ob);
            }
            int bi = 0x7fffffff;
            #pragma unroll
            for (int fc = 0; fc < 4; fc++) {
                unsigned long long mm = __ballot(vv[fc] == b);
                unsigned q16 = (unsigned)((mm >> (quad * 16)) & 0xFFFFu);
                if (bi == 0x7fffffff && q16)
                    bi = colQuadBase + fc * 16 + (__ffs(q16) - 1);
            }
            if (u == 0) {
                int rl = fr * 16 + quad * 4 + reg;   // local row 0..127
                ebf[w * 128 + rl] = b; esf[w * 128 + rl] = s; eif[w * 128 + rl] = bi;
            }
        }
    }
    __syncthreads();
    // coalesced partial stores: 128 contiguous rows per wave per array
    {
        const int base = cbi * BROWS + rowBase + wr * 128;
        pbest[base + lane]      = ebf[w * 128 + lane];
        pbest[base + 64 + lane] = ebf[w * 128 + 64 + lane];
        psec [base + lane]      = esf[w * 128 + lane];
        psec [base + 64 + lane] = esf[w * 128 + 64 + lane];
        pidx [base + lane]      = eif[w * 128 + lane];
        pidx [base + 64 + lane] = eif[w * 128 + 64 + lane];
    }
}

// ---------------- merge 32 partials per row; flag near-ties -----------------
__global__ __launch_bounds__(256) void reduce_rows(const float* __restrict__ pbest,
                                                   const float* __restrict__ psec,
                                                   const int* __restrict__ pidx,
                                                   float* __restrict__ out,
                                                   int* __restrict__ labels,
                                                   int* __restrict__ rlist,
                                                   int* __restrict__ ctr) {
    int row = blockIdx.x * 256 + threadIdx.x;    // grid 128
    float b = 3.4e38f, s = 3.4e38f; int bi = 0x7fffffff;
    for (int p = 0; p < 32; p++) {
        float v  = pbest[p * BROWS + row];
        float sv = psec [p * BROWS + row];
        int   vi = pidx [p * BROWS + row];
        if (v < b) { s = fminf(b, fminf(s, sv)); b = v; bi = vi; }
        else       { s = fminf(s, fminf(v, sv)); }
    }
    out[row] = (float)bi;
    labels[row] = bi;
    if (s - b < TAU) {
        int slot = atomicAdd(ctr, 1);
        if (slot < FCAP) rlist[slot] = row;
    }
}

// ---------------- exact fp32 rescore of flagged rows ------------------------
__global__ __launch_bounds__(256, 2) void fixup_dist(const float* __restrict__ x,
                                                     const float* __restrict__ cen,
                                                     const float* __restrict__ csq,
                                                     const int* __restrict__ rlist,
                                                     const int* __restrict__ ctr,
                                                     float* __restrict__ fbest,
                                                     int*   __restrict__ fidx) {
    int n = min(*ctr, FCAP);
    int tilebase = blockIdx.y * 128;
    if (tilebase >= n) return;

    __shared__ float xs[16][132];
    __shared__ float cs[16][132];
    __shared__ float redv[128][17];
    __shared__ int   redi[128][17];
    __shared__ int   rows[128];

    const int tid = threadIdx.x;
    if (tid < 128) {
        int ii = tilebase + tid;
        rows[tid] = (ii < n) ? rlist[ii] : 0;   // clamp: rlist not pre-zeroed
    }
    __syncthreads();

    const int ty = tid >> 4, tx = tid & 15;
    const int colBase = blockIdx.x * 128;

    float acc[8][8] = {};
    for (int dk = 0; dk < DD; dk += 16) {
        #pragma unroll
        for (int sI = 0; sI < 2; sI++) {
            int id = tid + sI * 256;
            int r  = id >> 2;
            int dc = (id & 3) * 4;
            float4 xv = *(const float4*)(x + (size_t)rows[r] * DD + dk + dc);
            xs[dc + 0][r] = xv.x + EPS; xs[dc + 1][r] = xv.y + EPS;
            xs[dc + 2][r] = xv.z + EPS; xs[dc + 3][r] = xv.w + EPS;
            float4 cv = *(const float4*)(cen + (size_t)(colBase + r) * DD + dk + dc);
            cs[dc + 0][r] = cv.x; cs[dc + 1][r] = cv.y;
            cs[dc + 2][r] = cv.z; cs[dc + 3][r] = cv.w;
        }
        __syncthreads();
        #pragma unroll
        for (int k = 0; k < 16; k++) {
            float4 a0 = *(const float4*)&xs[k][ty * 4];
            float4 a1 = *(const float4*)&xs[k][64 + ty * 4];
            float4 b0 = *(const float4*)&cs[k][tx * 4];
            float4 b1 = *(const float4*)&cs[k][64 + tx * 4];
            float a[8] = {a0.x, a0.y, a0.z, a0.w, a1.x, a1.y, a1.z, a1.w};
            float b[8] = {b0.x, b0.y, b0.z, b0.w, b1.x, b1.y, b1.z, b1.w};
            #pragma unroll
            for (int i = 0; i < 8; i++)
                #pragma unroll
                for (int j = 0; j < 8; j++)
                    acc[i][j] += a[i] * b[j];
        }
        __syncthreads();
    }

    float bv[8]; int bix[8];
    #pragma unroll
    for (int i = 0; i < 8; i++) { bv[i] = 3.4e38f; bix[i] = 0x7fffffff; }
    #pragma unroll
    for (int j = 0; j < 8; j++) {
        int col = colBase + ((j < 4) ? (tx * 4 + j) : (64 + tx * 4 + (j - 4)));
        float cq = csq[col];
        #pragma unroll
        for (int i = 0; i < 8; i++) {
            float v = cq - 2.0f * acc[i][j];
            if (v < bv[i] || (v == bv[i] && col < bix[i])) { bv[i] = v; bix[i] = col; }
        }
    }
    #pragma unroll
    for (int i = 0; i < 8; i++) {
        int r = (i < 4) ? (ty * 4 + i) : (64 + ty * 4 + (i - 4));
        redv[r][tx] = bv[i]; redi[r][tx] = bix[i];
    }
    __syncthreads();
    if (tid < 128) {
        float b = 3.4e38f; int bi = 0x7fffffff;
        #pragma unroll
        for (int t = 0; t < 16; t++) {
            float v = redv[tid][t]; int ix = redi[tid][t];
            if (v < b || (v == b && ix < bi)) { b = v; bi = ix; }
        }
        fbest[blockIdx.x * FCAP + tilebase + tid] = b;
        fidx [blockIdx.x * FCAP + tilebase + tid] = bi;
    }
}

__global__ __launch_bounds__(256) void fixup_reduce(const float* __restrict__ fbest,
                                                    const int* __restrict__ fidx,
                                                    const int* __restrict__ rlist,
                                                    const int* __restrict__ ctr,
                                                    float* __restrict__ out,
                                                    int* __restrict__ labels) {
    int s = blockIdx.x * 256 + threadIdx.x;      // grid 16
    int n = min(*ctr, FCAP);
    if (s >= n) return;
    float b = 3.4e38f; int bi = 0x7fffffff;
    for (int c = 0; c < 16; c++) {
        float v = fbest[c * FCAP + s]; int ix = fidx[c * FCAP + s];
        if (v < b || (v == b && ix < bi)) { b = v; bi = ix; }
    }
    int row = rlist[s];
    out[row] = (float)bi;
    labels[row] = bi;
}

// ---------------- gather assigned centroids ---------------------------------
__global__ __launch_bounds__(256) void gather(const float* __restrict__ cen,
                                              const int* __restrict__ labels,
                                              float* __restrict__ out) {
    __shared__ int lab[8];
    const int tid = threadIdx.x;
    const int rowBase = blockIdx.x * 8;
    if (tid < 8) lab[tid] = labels[rowBase + tid];
    __syncthreads();
    float* assigned = out + BROWS;
    #pragma unroll 4
    for (int s = tid; s < 8 * 128; s += 256) {
        int r = s >> 7;
        int f = (s & 127) * 4;
        float4 v = *(const float4*)(cen + (size_t)lab[r] * DD + f);
        *(float4*)(assigned + (size_t)(rowBase + r) * DD + f) = v;
    }
}

extern "C" void kernel_launch(void* const* d_in, const int* in_sizes, int n_in,
                              void* d_out, int out_size, void* d_ws, size_t ws_size,
                              hipStream_t stream) {
    const float* x   = (const float*)d_in[0];
    const float* cen = (const float*)d_in[1];

    char* base = (char*)d_ws;
    _Float16* xh   = (_Float16*)(base);                    // 32 MB
    _Float16* ch   = (_Float16*)(base + 33554432);         // 2 MB
    float* csq     = (float*)(base + 35651584);            // 8 KB
    float* pbest   = (float*)(base + 35659776);            // 4 MB
    float* psec    = (float*)(base + 39854080);            // 4 MB
    int*   pidx    = (int*)  (base + 44048384);            // 4 MB
    int*   labels  = (int*)  (base + 48242688);            // 128 KB
    int*   rlist   = (int*)  (base + 48373760);            // 16 KB
    float* fbest   = (float*)(base + 48390144);            // 256 KB
    int*   fidx    = (int*)  (base + 48652288);            // 256 KB
    int*   ctr     = (int*)  (base + 48914432);            // 4 B

    prep<<<KC / 4 + BROWS * DD / 4 / 256, 256, 0, stream>>>(x, cen, xh, ch, csq, ctr);
    dist_f16<<<dim3(BROWS / 256, KC / 256), 512, 0, stream>>>(xh, ch, csq, pbest, psec, pidx);
    reduce_rows<<<BROWS / 256, 256, 0, stream>>>(pbest, psec, pidx, (float*)d_out, labels, rlist, ctr);
    fixup_dist<<<dim3(KC / 128, FCAP / 128), 256, 0, stream>>>(x, cen, csq, rlist, ctr, fbest, fidx);
    fixup_reduce<<<FCAP / 256, 256, 0, stream>>>(fbest, fidx, rlist, ctr, (float*)d_out, labels);
    gather<<<BROWS / 8, 256, 0, stream>>>(cen, labels, (float*)d_out);
}

// Round 8
// 315.840 us; speedup vs baseline: 1.0094x; 1.0094x over previous
//
#include <hip/hip_runtime.h>
#include <hip/hip_bf16.h>

// KMeans assign via fp16 coarse MFMA + exact fp32 fixup of near-tie rows.
// argmin_k ||xe - c_k|| == argmin_k ( ||c_k||^2 - 2*xe.c_k ),  xe = x + 1e-6.
// Rows with coarse top2 gap < TAU=0.3 are exactly rescored in fp32.
//
// R6: LDS-port model (closes numerically: R4 = 80KB port-bytes/block-step
// / 85 B/cyc effective = 960 cyc = measured 102.7us; MfmaUtil == MFMA/port
// ratio). 256^2 halves port-bytes/MAC but R5's 80KB LDS broke 2-block/CU
// residency (occupancy 22% => 1 block/CU). Fix: A 2-buf + B 2-buf = 64KB
// exactly -> 2 blocks/CU guaranteed; vmcnt(0)/step drain covered by the
// sibling block (step ~1500cyc >> 900cyc HBM latency). setprio(1) around
// MFMA cluster (T5). Port floor ~41us; predict 50-75us.
// SQ_LDS_BANK_CONFLICT = fixed DMA-write cost per global_load_lds
// (8 cyc @256thr, 12 cyc @512thr; exact-count verified R1-R5).

#define EPS 1e-6f
#define TAU 0.3f

constexpr int BROWS = 32768;   // 8*4096 rows
constexpr int DD    = 512;
constexpr int KC    = 2048;    // centroids
constexpr int FCAP  = 4096;    // max flagged rows handled exactly
constexpr int NK    = DD / 32; // 16 K-steps

typedef _Float16 half8  __attribute__((ext_vector_type(8)));
typedef _Float16 half4v __attribute__((ext_vector_type(4)));
typedef float    f32x4  __attribute__((ext_vector_type(4)));

// ---------------- fused prep: x->fp16(+eps), centroids->fp16 + csq ----------
__global__ __launch_bounds__(256) void prep(const float* __restrict__ x,
                                            const float* __restrict__ cen,
                                            _Float16* __restrict__ xh,
                                            _Float16* __restrict__ ch,
                                            float* __restrict__ csq,
                                            int* __restrict__ ctr) {
    const int bid = blockIdx.x;
    if (bid < KC / 4) {
        // centroid block (grid 512 -> 2048 rows)
        if (bid == 0 && threadIdx.x == 0) *ctr = 0;
        int w = threadIdx.x >> 6, lane = threadIdx.x & 63;
        int c = bid * 4 + w;
        const float* row = cen + (size_t)c * DD;
        float4 v0 = *(const float4*)(row + lane * 8);
        float4 v1 = *(const float4*)(row + lane * 8 + 4);
        half8 h;
        h[0] = (_Float16)v0.x; h[1] = (_Float16)v0.y; h[2] = (_Float16)v0.z; h[3] = (_Float16)v0.w;
        h[4] = (_Float16)v1.x; h[5] = (_Float16)v1.y; h[6] = (_Float16)v1.z; h[7] = (_Float16)v1.w;
        *(half8*)(ch + (size_t)c * DD + lane * 8) = h;
        float s = v0.x*v0.x + v0.y*v0.y + v0.z*v0.z + v0.w*v0.w
                + v1.x*v1.x + v1.y*v1.y + v1.z*v1.z + v1.w*v1.w;
        #pragma unroll
        for (int off = 32; off > 0; off >>= 1) s += __shfl_down(s, off, 64);
        if (lane == 0) csq[c] = s;
    } else {
        size_t i = ((size_t)(bid - KC / 4) * 256 + threadIdx.x) * 4;
        float4 v = *(const float4*)(x + i);
        half4v h;
        h[0] = (_Float16)(v.x + EPS); h[1] = (_Float16)(v.y + EPS);
        h[2] = (_Float16)(v.z + EPS); h[3] = (_Float16)(v.w + EPS);
        *(half4v*)(xh + i) = h;
    }
}

// ---------------- coarse fp16 MFMA distance + per-row top2 ------------------
// 256x256 tile, 8 waves (2 row-groups x 4 col-groups), wave tile 128x64.
// A 2-buf + B 2-buf = 64KB -> 2 blocks/CU; vmcnt(0)+s_barrier per step.
__global__ __launch_bounds__(512, 2) void dist_f16(const _Float16* __restrict__ xh,
                                                   const _Float16* __restrict__ ch,
                                                   const float* __restrict__ csq,
                                                   float* __restrict__ pbest,
                                                   float* __restrict__ psec,
                                                   int*   __restrict__ pidx) {
    // A bufs: smem + {0,1}*8192 halfs; B bufs: smem + 16384 + {0,1}*8192.
    __shared__ __align__(16) _Float16 smem[4 * 8192];     // 64 KB exactly

    const int tid = threadIdx.x;
    const int w = tid >> 6, lane = tid & 63;
    const int wr = w >> 2, wc = w & 3;
    const int quad = lane >> 4, u = lane & 15;
    const int rowBase = blockIdx.x * 256;
    const int colBase = blockIdx.y * 256;

    // csq loads pinned before the pipeline (cannot cross the asm fences).
    float cq[4];
    #pragma unroll
    for (int fc = 0; fc < 4; fc++) cq[fc] = csq[colBase + wc * 64 + fc * 16 + u];

    // Staging granules (16B each), g in [0,1024): LDS row g>>2, slot g&3.
    const int g0 = 128 * w + lane;
    const int g1 = g0 + 64;
    const int r0 = g0 >> 2, h0 = g0 & 3;
    const int r1 = g1 >> 2, h1 = g1 & 3;
    const _Float16* pa0 = xh + (size_t)(rowBase + r0) * DD + h0 * 8;
    const _Float16* pa1 = xh + (size_t)(rowBase + r1) * DD + h1 * 8;
    const _Float16* pb0 = ch + (size_t)(colBase + r0) * DD + h0 * 8;
    const _Float16* pb1 = ch + (size_t)(colBase + r1) * DD + h1 * 8;

    auto stage = [&](int kt) {   // 4 global_load_lds per thread (A + B)
        _Float16* da = smem + (kt & 1) * 8192;
        _Float16* db = smem + 16384 + (kt & 1) * 8192;
        const int off = kt * 32;
        __builtin_amdgcn_global_load_lds(
            (const __attribute__((address_space(1))) void*)(pa0 + off),
            (__attribute__((address_space(3))) void*)(da + g0 * 8), 16, 0, 0);
        __builtin_amdgcn_global_load_lds(
            (const __attribute__((address_space(1))) void*)(pa1 + off),
            (__attribute__((address_space(3))) void*)(da + g1 * 8), 16, 0, 0);
        __builtin_amdgcn_global_load_lds(
            (const __attribute__((address_space(1))) void*)(pb0 + off),
            (__attribute__((address_space(3))) void*)(db + g0 * 8), 16, 0, 0);
        __builtin_amdgcn_global_load_lds(
            (const __attribute__((address_space(1))) void*)(pb1 + off),
            (__attribute__((address_space(3))) void*)(db + g1 * 8), 16, 0, 0);
    };

    f32x4 acc[8][4] = {};

    stage(0);   // 4 loads/thread outstanding

    for (int kc = 0; kc < NK; kc++) {
        // tile kc must be resident; sibling block covers this drain.
        asm volatile("s_waitcnt vmcnt(0)" ::: "memory");
        __builtin_amdgcn_s_barrier();
        asm volatile("" ::: "memory");
        __builtin_amdgcn_sched_barrier(0);

        if (kc + 1 < NK) stage(kc + 1);   // into bufs (kc+1)&1 (readers retired)

        const _Float16* abuf = smem + (kc & 1) * 8192;
        const _Float16* bbuf = smem + 16384 + (kc & 1) * 8192;
        half8 af[8], bf[4];
        #pragma unroll
        for (int f = 0; f < 8; f++)
            af[f] = *(const half8*)(abuf + (wr * 128 + f * 16 + u) * 32 + quad * 8);
        #pragma unroll
        for (int f = 0; f < 4; f++)
            bf[f] = *(const half8*)(bbuf + (wc * 64 + f * 16 + u) * 32 + quad * 8);

        __builtin_amdgcn_s_setprio(1);
        #pragma unroll
        for (int fr = 0; fr < 8; fr++)
            #pragma unroll
            for (int fc = 0; fc < 4; fc++)
                acc[fr][fc] = __builtin_amdgcn_mfma_f32_16x16x32_f16(af[fr], bf[fc], acc[fr][fc], 0, 0, 0);
        __builtin_amdgcn_s_setprio(0);
    }

    __syncthreads();   // all LDS reads retired; safe to overlay epilogue staging

    // epilogue staging overlays the A-buffers (12 KB of 64 KB).
    float* ebf = (float*)smem;           // [8][128]
    float* esf = ebf + 8 * 128;          // [8][128]
    int*   eif = (int*)(esf + 8 * 128);  // [8][128]

    const int cbi = blockIdx.y * 4 + wc;
    const int colQuadBase = colBase + wc * 64;

    #pragma unroll
    for (int fr = 0; fr < 8; fr++) {
        #pragma unroll
        for (int reg = 0; reg < 4; reg++) {
            float vv[4];
            #pragma unroll
            for (int fc = 0; fc < 4; fc++) vv[fc] = cq[fc] - 2.0f * acc[fr][fc][reg];
            // top2 of 4 (min/max network); no coarse tie-break needed
            float mn01 = fminf(vv[0], vv[1]), mx01 = fmaxf(vv[0], vv[1]);
            float mn23 = fminf(vv[2], vv[3]), mx23 = fmaxf(vv[2], vv[3]);
            float b = fminf(mn01, mn23);
            float s = fminf(fmaxf(mn01, mn23), fminf(mx01, mx23));
            #pragma unroll
            for (int m = 1; m < 16; m <<= 1) {   // butterfly within quad
                float ob = __shfl_xor(b, m, 64);
                float os = __shfl_xor(s, m, 64);
                s = fminf(fminf(s, os), fmaxf(b, ob));
                b = fminf(b, ob);
            }
            int bi = 0x7fffffff;
            #pragma unroll
            for (int fc = 0; fc < 4; fc++) {
                unsigned long long mm = __ballot(vv[fc] == b);
                unsigned q16 = (unsigned)((mm >> (quad * 16)) & 0xFFFFu);
                if (bi == 0x7fffffff && q16)
                    bi = colQuadBase + fc * 16 + (__ffs(q16) - 1);
            }
            if (u == 0) {
                int rl = fr * 16 + quad * 4 + reg;   // local row 0..127
                ebf[w * 128 + rl] = b; esf[w * 128 + rl] = s; eif[w * 128 + rl] = bi;
            }
        }
    }
    __syncthreads();
    // coalesced partial stores: 128 contiguous rows per wave per array
    {
        const int base = cbi * BROWS + rowBase + wr * 128;
        pbest[base + lane]      = ebf[w * 128 + lane];
        pbest[base + 64 + lane] = ebf[w * 128 + 64 + lane];
        psec [base + lane]      = esf[w * 128 + lane];
        psec [base + 64 + lane] = esf[w * 128 + 64 + lane];
        pidx [base + lane]      = eif[w * 128 + lane];
        pidx [base + 64 + lane] = eif[w * 128 + 64 + lane];
    }
}

// ---------------- merge 32 partials per row; flag near-ties -----------------
__global__ __launch_bounds__(256) void reduce_rows(const float* __restrict__ pbest,
                                                   const float* __restrict__ psec,
                                                   const int* __restrict__ pidx,
                                                   float* __restrict__ out,
                                                   int* __restrict__ labels,
                                                   int* __restrict__ rlist,
                                                   int* __restrict__ ctr) {
    int row = blockIdx.x * 256 + threadIdx.x;    // grid 128
    float b = 3.4e38f, s = 3.4e38f; int bi = 0x7fffffff;
    for (int p = 0; p < 32; p++) {
        float v  = pbest[p * BROWS + row];
        float sv = psec [p * BROWS + row];
        int   vi = pidx [p * BROWS + row];
        if (v < b) { s = fminf(b, fminf(s, sv)); b = v; bi = vi; }
        else       { s = fminf(s, fminf(v, sv)); }
    }
    out[row] = (float)bi;
    labels[row] = bi;
    if (s - b < TAU) {
        int slot = atomicAdd(ctr, 1);
        if (slot < FCAP) rlist[slot] = row;
    }
}

// ---------------- exact fp32 rescore of flagged rows ------------------------
__global__ __launch_bounds__(256, 2) void fixup_dist(const float* __restrict__ x,
                                                     const float* __restrict__ cen,
                                                     const float* __restrict__ csq,
                                                     const int* __restrict__ rlist,
                                                     const int* __restrict__ ctr,
                                                     float* __restrict__ fbest,
                                                     int*   __restrict__ fidx) {
    int n = min(*ctr, FCAP);
    int tilebase = blockIdx.y * 128;
    if (tilebase >= n) return;

    __shared__ float xs[16][132];
    __shared__ float cs[16][132];
    __shared__ float redv[128][17];
    __shared__ int   redi[128][17];
    __shared__ int   rows[128];

    const int tid = threadIdx.x;
    if (tid < 128) {
        int ii = tilebase + tid;
        rows[tid] = (ii < n) ? rlist[ii] : 0;   // clamp: rlist not pre-zeroed
    }
    __syncthreads();

    const int ty = tid >> 4, tx = tid & 15;
    const int colBase = blockIdx.x * 128;

    float acc[8][8] = {};
    for (int dk = 0; dk < DD; dk += 16) {
        #pragma unroll
        for (int sI = 0; sI < 2; sI++) {
            int id = tid + sI * 256;
            int r  = id >> 2;
            int dc = (id & 3) * 4;
            float4 xv = *(const float4*)(x + (size_t)rows[r] * DD + dk + dc);
            xs[dc + 0][r] = xv.x + EPS; xs[dc + 1][r] = xv.y + EPS;
            xs[dc + 2][r] = xv.z + EPS; xs[dc + 3][r] = xv.w + EPS;
            float4 cv = *(const float4*)(cen + (size_t)(colBase + r) * DD + dk + dc);
            cs[dc + 0][r] = cv.x; cs[dc + 1][r] = cv.y;
            cs[dc + 2][r] = cv.z; cs[dc + 3][r] = cv.w;
        }
        __syncthreads();
        #pragma unroll
        for (int k = 0; k < 16; k++) {
            float4 a0 = *(const float4*)&xs[k][ty * 4];
            float4 a1 = *(const float4*)&xs[k][64 + ty * 4];
            float4 b0 = *(const float4*)&cs[k][tx * 4];
            float4 b1 = *(const float4*)&cs[k][64 + tx * 4];
            float a[8] = {a0.x, a0.y, a0.z, a0.w, a1.x, a1.y, a1.z, a1.w};
            float b[8] = {b0.x, b0.y, b0.z, b0.w, b1.x, b1.y, b1.z, b1.w};
            #pragma unroll
            for (int i = 0; i < 8; i++)
                #pragma unroll
                for (int j = 0; j < 8; j++)
                    acc[i][j] += a[i] * b[j];
        }
        __syncthreads();
    }

    float bv[8]; int bix[8];
    #pragma unroll
    for (int i = 0; i < 8; i++) { bv[i] = 3.4e38f; bix[i] = 0x7fffffff; }
    #pragma unroll
    for (int j = 0; j < 8; j++) {
        int col = colBase + ((j < 4) ? (tx * 4 + j) : (64 + tx * 4 + (j - 4)));
        float cq = csq[col];
        #pragma unroll
        for (int i = 0; i < 8; i++) {
            float v = cq - 2.0f * acc[i][j];
            if (v < bv[i] || (v == bv[i] && col < bix[i])) { bv[i] = v; bix[i] = col; }
        }
    }
    #pragma unroll
    for (int i = 0; i < 8; i++) {
        int r = (i < 4) ? (ty * 4 + i) : (64 + ty * 4 + (i - 4));
        redv[r][tx] = bv[i]; redi[r][tx] = bix[i];
    }
    __syncthreads();
    if (tid < 128) {
        float b = 3.4e38f; int bi = 0x7fffffff;
        #pragma unroll
        for (int t = 0; t < 16; t++) {
            float v = redv[tid][t]; int ix = redi[tid][t];
            if (v < b || (v == b && ix < bi)) { b = v; bi = ix; }
        }
        fbest[blockIdx.x * FCAP + tilebase + tid] = b;
        fidx [blockIdx.x * FCAP + tilebase + tid] = bi;
    }
}

__global__ __launch_bounds__(256) void fixup_reduce(const float* __restrict__ fbest,
                                                    const int* __restrict__ fidx,
                                                    const int* __restrict__ rlist,
                                                    const int* __restrict__ ctr,
                                                    float* __restrict__ out,
                                                    int* __restrict__ labels) {
    int s = blockIdx.x * 256 + threadIdx.x;      // grid 16
    int n = min(*ctr, FCAP);
    if (s >= n) return;
    float b = 3.4e38f; int bi = 0x7fffffff;
    for (int c = 0; c < 16; c++) {
        float v = fbest[c * FCAP + s]; int ix = fidx[c * FCAP + s];
        if (v < b || (v == b && ix < bi)) { b = v; bi = ix; }
    }
    int row = rlist[s];
    out[row] = (float)bi;
    labels[row] = bi;
}

// ---------------- gather assigned centroids ---------------------------------
__global__ __launch_bounds__(256) void gather(const float* __restrict__ cen,
                                              const int* __restrict__ labels,
                                              float* __restrict__ out) {
    __shared__ int lab[8];
    const int tid = threadIdx.x;
    const int rowBase = blockIdx.x * 8;
    if (tid < 8) lab[tid] = labels[rowBase + tid];
    __syncthreads();
    float* assigned = out + BROWS;
    #pragma unroll 4
    for (int s = tid; s < 8 * 128; s += 256) {
        int r = s >> 7;
        int f = (s & 127) * 4;
        float4 v = *(const float4*)(cen + (size_t)lab[r] * DD + f);
        *(float4*)(assigned + (size_t)(rowBase + r) * DD + f) = v;
    }
}

extern "C" void kernel_launch(void* const* d_in, const int* in_sizes, int n_in,
                              void* d_out, int out_size, void* d_ws, size_t ws_size,
                              hipStream_t stream) {
    const float* x   = (const float*)d_in[0];
    const float* cen = (const float*)d_in[1];

    char* base = (char*)d_ws;
    _Float16* xh   = (_Float16*)(base);                    // 32 MB
    _Float16* ch   = (_Float16*)(base + 33554432);         // 2 MB
    float* csq     = (float*)(base + 35651584);            // 8 KB
    float* pbest   = (float*)(base + 35659776);            // 4 MB
    float* psec    = (float*)(base + 39854080);            // 4 MB
    int*   pidx    = (int*)  (base + 44048384);            // 4 MB
    int*   labels  = (int*)  (base + 48242688);            // 128 KB
    int*   rlist   = (int*)  (base + 48373760);            // 16 KB
    float* fbest   = (float*)(base + 48390144);            // 256 KB
    int*   fidx    = (int*)  (base + 48652288);            // 256 KB
    int*   ctr     = (int*)  (base + 48914432);            // 4 B

    prep<<<KC / 4 + BROWS * DD / 4 / 256, 256, 0, stream>>>(x, cen, xh, ch, csq, ctr);
    dist_f16<<<dim3(BROWS / 256, KC / 256), 512, 0, stream>>>(xh, ch, csq, pbest, psec, pidx);
    reduce_rows<<<BROWS / 256, 256, 0, stream>>>(pbest, psec, pidx, (float*)d_out, labels, rlist, ctr);
    fixup_dist<<<dim3(KC / 128, FCAP / 128), 256, 0, stream>>>(x, cen, csq, rlist, ctr, fbest, fidx);
    fixup_reduce<<<FCAP / 256, 256, 0, stream>>>(fbest, fidx, rlist, ctr, (float*)d_out, labels);
    gather<<<BROWS / 8, 256, 0, stream>>>(cen, labels, (float*)d_out);
}

// Round 9
// 274.380 us; speedup vs baseline: 1.1620x; 1.1511x over previous
//
#include <hip/hip_runtime.h>
#include <hip/hip_bf16.h>

// KMeans assign via fp16 coarse MFMA + fp16x2-limb MFMA fixup of near-ties.
// argmin_k ||xe - c_k|| == argmin_k ( ||c_k||^2 - 2*xe.c_k ),  xe = x + 1e-6.
// Rows with coarse top2 gap < TAU=0.3 are exactly rescored (fp32-equivalent).
//
// R7: (a) dist_f16 reverted to R4 verbatim (proven 102.7us; R5/R6 256^2
// variants are REGISTER-locked to 1 block/CU: 232-256 unified regs/thread
// -> 2 waves/SIMD -> no sibling-block latency cover. 128^2 @128 regs gives
// 16 waves/CU). (b) fixup_dist rewritten as fp16 two-limb MFMA GEMM:
// v = hi + lo (11+11 mantissa bits); dot = hh + hl + lh into one fp32 acc
// (ll dropped: ~5e-7 abs, 4 orders below fp32-reference noise). Stages raw
// fp32 x/cen via global_load_lds with both-sides XOR slot swizzle
// (slot ^= row&7; fp32 rows are 16-way conflicted unswizzled), limb-split
// in-register. ~37% of coarse-dist MACs vs the old scalar-fp32 155-TF-pipe
// version (~120us inferred).
// SQ_LDS_BANK_CONFLICT = fixed DMA-write cost per global_load_lds
// (exact-count verified R1-R6).

#define EPS 1e-6f
#define TAU 0.3f

constexpr int BROWS = 32768;   // 8*4096 rows
constexpr int DD    = 512;
constexpr int KC    = 2048;    // centroids
constexpr int FCAP  = 4096;    // max flagged rows handled exactly
constexpr int NK    = DD / 32; // 16 K-steps

typedef _Float16 half8  __attribute__((ext_vector_type(8)));
typedef _Float16 half4v __attribute__((ext_vector_type(4)));
typedef float    f32x4  __attribute__((ext_vector_type(4)));

// ---------------- fused prep: x->fp16(+eps), centroids->fp16 + csq ----------
__global__ __launch_bounds__(256) void prep(const float* __restrict__ x,
                                            const float* __restrict__ cen,
                                            _Float16* __restrict__ xh,
                                            _Float16* __restrict__ ch,
                                            float* __restrict__ csq,
                                            int* __restrict__ ctr) {
    const int bid = blockIdx.x;
    if (bid < KC / 4) {
        // centroid block (grid 512 -> 2048 rows)
        if (bid == 0 && threadIdx.x == 0) *ctr = 0;
        int w = threadIdx.x >> 6, lane = threadIdx.x & 63;
        int c = bid * 4 + w;
        const float* row = cen + (size_t)c * DD;
        float4 v0 = *(const float4*)(row + lane * 8);
        float4 v1 = *(const float4*)(row + lane * 8 + 4);
        half8 h;
        h[0] = (_Float16)v0.x; h[1] = (_Float16)v0.y; h[2] = (_Float16)v0.z; h[3] = (_Float16)v0.w;
        h[4] = (_Float16)v1.x; h[5] = (_Float16)v1.y; h[6] = (_Float16)v1.z; h[7] = (_Float16)v1.w;
        *(half8*)(ch + (size_t)c * DD + lane * 8) = h;
        float s = v0.x*v0.x + v0.y*v0.y + v0.z*v0.z + v0.w*v0.w
                + v1.x*v1.x + v1.y*v1.y + v1.z*v1.z + v1.w*v1.w;
        #pragma unroll
        for (int off = 32; off > 0; off >>= 1) s += __shfl_down(s, off, 64);
        if (lane == 0) csq[c] = s;
    } else {
        size_t i = ((size_t)(bid - KC / 4) * 256 + threadIdx.x) * 4;
        float4 v = *(const float4*)(x + i);
        half4v h;
        h[0] = (_Float16)(v.x + EPS); h[1] = (_Float16)(v.y + EPS);
        h[2] = (_Float16)(v.z + EPS); h[3] = (_Float16)(v.w + EPS);
        *(half4v*)(xh + i) = h;
    }
}

// ---------------- coarse fp16 MFMA distance + per-row top2 (R4 verbatim) ----
// 128x128 tile, 4 waves of 64x64. A 3-buf (stage k+2), B 2-buf (stage k+1),
// counted s_waitcnt vmcnt(2) + raw s_barrier per K-step. LDS 40KB.
__global__ __launch_bounds__(256, 4) void dist_f16(const _Float16* __restrict__ xh,
                                                   const _Float16* __restrict__ ch,
                                                   const float* __restrict__ csq,
                                                   float* __restrict__ pbest,
                                                   float* __restrict__ psec,
                                                   int*   __restrict__ pidx) {
    // A tiles: smem + {0,1,2}*4096 halfs; B tiles: smem + 12288 + {0,1}*4096.
    __shared__ __align__(16) _Float16 smem[5 * 4096];     // 40 KB exactly

    const int tid = threadIdx.x;
    const int w = tid >> 6, lane = tid & 63;
    const int wr = w >> 1, wc = w & 1;
    const int quad = lane >> 4, u = lane & 15;
    const int rowBase = blockIdx.x * 128;
    const int colBase = blockIdx.y * 128;

    // csq loads pinned before the pipeline (cannot cross the asm fences).
    float cq[4];
    #pragma unroll
    for (int fc = 0; fc < 4; fc++) cq[fc] = csq[colBase + wc * 64 + fc * 16 + u];

    // Staging granules (16B each), g in [0,512): LDS row g>>2, slot g&3.
    const int g0 = 128 * w + lane;
    const int g1 = g0 + 64;
    const int r0 = g0 >> 2, h0 = g0 & 3;
    const int r1 = g1 >> 2, h1 = g1 & 3;
    const _Float16* pa0 = xh + (size_t)(rowBase + r0) * DD + h0 * 8;
    const _Float16* pa1 = xh + (size_t)(rowBase + r1) * DD + h1 * 8;
    const _Float16* pb0 = ch + (size_t)(colBase + r0) * DD + h0 * 8;
    const _Float16* pb1 = ch + (size_t)(colBase + r1) * DD + h1 * 8;

    auto stageA = [&](int kt) {   // 2 global_load_lds per thread
        _Float16* dst = smem + (kt % 3) * 4096;
        const int off = kt * 32;
        __builtin_amdgcn_global_load_lds(
            (const __attribute__((address_space(1))) void*)(pa0 + off),
            (__attribute__((address_space(3))) void*)(dst + g0 * 8), 16, 0, 0);
        __builtin_amdgcn_global_load_lds(
            (const __attribute__((address_space(1))) void*)(pa1 + off),
            (__attribute__((address_space(3))) void*)(dst + g1 * 8), 16, 0, 0);
    };
    auto stageB = [&](int kt) {   // 2 global_load_lds per thread
        _Float16* dst = smem + 12288 + (kt % 2) * 4096;
        const int off = kt * 32;
        __builtin_amdgcn_global_load_lds(
            (const __attribute__((address_space(1))) void*)(pb0 + off),
            (__attribute__((address_space(3))) void*)(dst + g0 * 8), 16, 0, 0);
        __builtin_amdgcn_global_load_lds(
            (const __attribute__((address_space(1))) void*)(pb1 + off),
            (__attribute__((address_space(3))) void*)(dst + g1 * 8), 16, 0, 0);
    };

    f32x4 acc[4][4] = {};

    // prologue: queue = [A0, B0, A1] (6 loads outstanding)
    stageA(0); stageB(0); stageA(1);

    #pragma unroll
    for (int kc = 0; kc < NK; kc++) {
        // wait for tiles A(kc), B(kc); leave A(kc+1)'s 2 loads in flight.
        if (kc + 1 < NK) asm volatile("s_waitcnt vmcnt(2)" ::: "memory");
        else             asm volatile("s_waitcnt vmcnt(0)" ::: "memory");
        __builtin_amdgcn_s_barrier();
        asm volatile("" ::: "memory");
        __builtin_amdgcn_sched_barrier(0);

        if (kc + 1 < NK) stageB(kc + 1);   // into bbuf[(kc+1)%2] (read kc-1, retired)
        if (kc + 2 < NK) stageA(kc + 2);   // into abuf[(kc+2)%3] (read kc-1, retired)

        const _Float16* abuf = smem + (kc % 3) * 4096;
        const _Float16* bbuf = smem + 12288 + (kc % 2) * 4096;
        half8 af[4], bf[4];
        #pragma unroll
        for (int f = 0; f < 4; f++) {
            af[f] = *(const half8*)(abuf + (wr * 64 + f * 16 + u) * 32 + quad * 8);
            bf[f] = *(const half8*)(bbuf + (wc * 64 + f * 16 + u) * 32 + quad * 8);
        }
        #pragma unroll
        for (int fr = 0; fr < 4; fr++)
            #pragma unroll
            for (int fc = 0; fc < 4; fc++)
                acc[fr][fc] = __builtin_amdgcn_mfma_f32_16x16x32_f16(af[fr], bf[fc], acc[fr][fc], 0, 0, 0);
    }

    __syncthreads();   // all LDS reads retired; safe to overlay epilogue staging

    // epilogue staging overlays the A-buffers (3 KB of 40 KB).
    float* ebf = (float*)smem;           // [4][64]
    float* esf = ebf + 256;              // [4][64]
    int*   eif = (int*)(esf + 256);      // [4][64]

    const int cbi = blockIdx.y * 2 + wc;
    const int colQuadBase = colBase + wc * 64;

    #pragma unroll
    for (int fr = 0; fr < 4; fr++) {
        #pragma unroll
        for (int reg = 0; reg < 4; reg++) {
            float vv[4];
            #pragma unroll
            for (int fc = 0; fc < 4; fc++) vv[fc] = cq[fc] - 2.0f * acc[fr][fc][reg];
            // top2 of 4 (min/max network); no coarse tie-break needed
            float mn01 = fminf(vv[0], vv[1]), mx01 = fmaxf(vv[0], vv[1]);
            float mn23 = fminf(vv[2], vv[3]), mx23 = fmaxf(vv[2], vv[3]);
            float b = fminf(mn01, mn23);
            float s = fminf(fmaxf(mn01, mn23), fminf(mx01, mx23));
            #pragma unroll
            for (int m = 1; m < 16; m <<= 1) {   // butterfly within quad
                float ob = __shfl_xor(b, m, 64);
                float os = __shfl_xor(s, m, 64);
                s = fminf(fminf(s, os), fmaxf(b, ob));
                b = fminf(b, ob);
            }
            int bi = 0x7fffffff;
            #pragma unroll
            for (int fc = 0; fc < 4; fc++) {
                unsigned long long mm = __ballot(vv[fc] == b);
                unsigned q16 = (unsigned)((mm >> (quad * 16)) & 0xFFFFu);
                if (bi == 0x7fffffff && q16)
                    bi = colQuadBase + fc * 16 + (__ffs(q16) - 1);
            }
            if (u == 0) {
                int rl = fr * 16 + quad * 4 + reg;   // local row 0..63
                ebf[w * 64 + rl] = b; esf[w * 64 + rl] = s; eif[w * 64 + rl] = bi;
            }
        }
    }
    __syncthreads();
    // coalesced partial stores: 64 contiguous rows per wave per array
    {
        const int base = cbi * BROWS + rowBase + wr * 64;
        pbest[base + lane] = ebf[w * 64 + lane];
        psec [base + lane] = esf[w * 64 + lane];
        pidx [base + lane] = eif[w * 64 + lane];
    }
}

// ---------------- merge 32 partials per row; flag near-ties -----------------
__global__ __launch_bounds__(256) void reduce_rows(const float* __restrict__ pbest,
                                                   const float* __restrict__ psec,
                                                   const int* __restrict__ pidx,
                                                   float* __restrict__ out,
                                                   int* __restrict__ labels,
                                                   int* __restrict__ rlist,
                                                   int* __restrict__ ctr) {
    int row = blockIdx.x * 256 + threadIdx.x;    // grid 128
    float b = 3.4e38f, s = 3.4e38f; int bi = 0x7fffffff;
    for (int p = 0; p < 32; p++) {
        float v  = pbest[p * BROWS + row];
        float sv = psec [p * BROWS + row];
        int   vi = pidx [p * BROWS + row];
        if (v < b) { s = fminf(b, fminf(s, sv)); b = v; bi = vi; }
        else       { s = fminf(s, fminf(v, sv)); }
    }
    out[row] = (float)bi;
    labels[row] = bi;
    if (s - b < TAU) {
        int slot = atomicAdd(ctr, 1);
        if (slot < FCAP) rlist[slot] = row;
    }
}

// ---------------- fp16x2-limb MFMA rescore of flagged rows ------------------
// 128x128 tile, 4 waves of 64x64. Stages raw fp32 x/cen (global_load_lds,
// XOR slot swizzle), splits to fp16 hi/lo limbs in-register, accumulates
// hh+hl+lh into one fp32 acc (48 MFMA/step/wave). ll dropped (~5e-7 abs).
__global__ __launch_bounds__(256, 2) void fixup_dist(const float* __restrict__ x,
                                                     const float* __restrict__ cen,
                                                     const float* __restrict__ csq,
                                                     const int* __restrict__ rlist,
                                                     const int* __restrict__ ctr,
                                                     float* __restrict__ fbest,
                                                     int*   __restrict__ fidx) {
    int n = min(*ctr, FCAP);
    int tilebase = blockIdx.y * 128;
    if (tilebase >= n) return;

    __shared__ __align__(16) float asmem[2][128 * 32];   // 32 KB
    __shared__ __align__(16) float bsmem[2][128 * 32];   // 32 KB
    __shared__ int   rows_s[128];
    __shared__ float fb[2][128];
    __shared__ int   fi[2][128];

    const int tid = threadIdx.x;
    if (tid < 128) {
        int ii = tilebase + tid;
        rows_s[tid] = (ii < n) ? rlist[ii] : rlist[0];   // clamp (dup row 0's entry)
    }
    __syncthreads();

    const int w = tid >> 6, lane = tid & 63;
    const int wr = w >> 1, wc = w & 1;
    const int quad = lane >> 4, u = lane & 15;
    const int colBase = blockIdx.x * 128;

    // Staging granules (16B = 4 floats), g in [0,1024): row g>>3, slot g&7.
    // Both-sides XOR swizzle: source chunk = slot ^ (row&7); read applies same.
    const float* pa[4]; const float* pb[4]; int ldsg[4];
    #pragma unroll
    for (int j = 0; j < 4; j++) {
        int g = j * 256 + tid;         // = j*256 + w*64 + lane (lane-contiguous)
        int r = g >> 3, s = (g & 7) ^ (r & 7);
        pa[j] = x   + (size_t)rows_s[r] * DD + s * 4;
        pb[j] = cen + (size_t)(colBase + r) * DD + s * 4;
        ldsg[j] = g * 4;               // float offset (16B granule)
    }

    auto stage = [&](int kt) {   // 8 global_load_lds per thread
        float* da = asmem[kt & 1];
        float* db = bsmem[kt & 1];
        const int off = kt * 32;
        #pragma unroll
        for (int j = 0; j < 4; j++) {
            __builtin_amdgcn_global_load_lds(
                (const __attribute__((address_space(1))) void*)(pa[j] + off),
                (__attribute__((address_space(3))) void*)(da + ldsg[j]), 16, 0, 0);
            __builtin_amdgcn_global_load_lds(
                (const __attribute__((address_space(1))) void*)(pb[j] + off),
                (__attribute__((address_space(3))) void*)(db + ldsg[j]), 16, 0, 0);
        }
    };

    f32x4 acc[4][4] = {};
    stage(0);

    for (int kc = 0; kc < NK; kc++) {
        asm volatile("s_waitcnt vmcnt(0)" ::: "memory");
        __builtin_amdgcn_s_barrier();
        asm volatile("" ::: "memory");
        __builtin_amdgcn_sched_barrier(0);
        if (kc + 1 < NK) stage(kc + 1);

        const float* ab = asmem[kc & 1];
        const float* bb = bsmem[kc & 1];
        half8 aH[4], aL[4], bH[4], bL[4];
        #pragma unroll
        for (int f = 0; f < 4; f++) {
            {   // A frag: rows of x (add EPS), k-chunk quad*8..+7
                const float* base = ab + (wr * 64 + f * 16 + u) * 32;
                int s0 = ((quad << 1) | 0) ^ (u & 7);
                int s1 = ((quad << 1) | 1) ^ (u & 7);
                float4 v0 = *(const float4*)(base + s0 * 4);
                float4 v1 = *(const float4*)(base + s1 * 4);
                float fs[8] = {v0.x, v0.y, v0.z, v0.w, v1.x, v1.y, v1.z, v1.w};
                #pragma unroll
                for (int e = 0; e < 8; e++) {
                    float fe = fs[e] + EPS;
                    _Float16 hi = (_Float16)fe;
                    aH[f][e] = hi;
                    aL[f][e] = (_Float16)(fe - (float)hi);
                }
            }
            {   // B frag: rows of cen (no EPS)
                const float* base = bb + (wc * 64 + f * 16 + u) * 32;
                int s0 = ((quad << 1) | 0) ^ (u & 7);
                int s1 = ((quad << 1) | 1) ^ (u & 7);
                float4 v0 = *(const float4*)(base + s0 * 4);
                float4 v1 = *(const float4*)(base + s1 * 4);
                float fs[8] = {v0.x, v0.y, v0.z, v0.w, v1.x, v1.y, v1.z, v1.w};
                #pragma unroll
                for (int e = 0; e < 8; e++) {
                    float fe = fs[e];
                    _Float16 hi = (_Float16)fe;
                    bH[f][e] = hi;
                    bL[f][e] = (_Float16)(fe - (float)hi);
                }
            }
        }
        #pragma unroll
        for (int fr = 0; fr < 4; fr++)
            #pragma unroll
            for (int fc = 0; fc < 4; fc++) {
                acc[fr][fc] = __builtin_amdgcn_mfma_f32_16x16x32_f16(aH[fr], bL[fc], acc[fr][fc], 0, 0, 0);
                acc[fr][fc] = __builtin_amdgcn_mfma_f32_16x16x32_f16(aL[fr], bH[fc], acc[fr][fc], 0, 0, 0);
                acc[fr][fc] = __builtin_amdgcn_mfma_f32_16x16x32_f16(aH[fr], bH[fc], acc[fr][fc], 0, 0, 0);
            }
    }

    // per-row argmin with index tie-break (final authority)
    float cqv[4];
    #pragma unroll
    for (int fc = 0; fc < 4; fc++) cqv[fc] = csq[colBase + wc * 64 + fc * 16 + u];
    const int colQuadBase = colBase + wc * 64;

    #pragma unroll
    for (int fr = 0; fr < 4; fr++) {
        #pragma unroll
        for (int reg = 0; reg < 4; reg++) {
            float b = 3.4e38f; int bi = 0x7fffffff;
            #pragma unroll
            for (int fc = 0; fc < 4; fc++) {
                float v = cqv[fc] - 2.0f * acc[fr][fc][reg];
                int c = colQuadBase + fc * 16 + u;
                if (v < b || (v == b && c < bi)) { b = v; bi = c; }
            }
            #pragma unroll
            for (int m = 1; m < 16; m <<= 1) {   // butterfly within quad
                float ob = __shfl_xor(b, m, 64);
                int  obi = __shfl_xor(bi, m, 64);
                if (ob < b || (ob == b && obi < bi)) { b = ob; bi = obi; }
            }
            if (u == 0) {
                int rl = wr * 64 + fr * 16 + quad * 4 + reg;   // local row 0..127
                fb[wc][rl] = b; fi[wc][rl] = bi;
            }
        }
    }
    __syncthreads();
    if (tid < 128) {
        float b0 = fb[0][tid]; int i0 = fi[0][tid];
        float b1 = fb[1][tid]; int i1 = fi[1][tid];
        float b; int bi;
        if (b1 < b0 || (b1 == b0 && i1 < i0)) { b = b1; bi = i1; }
        else                                  { b = b0; bi = i0; }
        fbest[blockIdx.x * FCAP + tilebase + tid] = b;
        fidx [blockIdx.x * FCAP + tilebase + tid] = bi;
    }
}

__global__ __launch_bounds__(256) void fixup_reduce(const float* __restrict__ fbest,
                                                    const int* __restrict__ fidx,
                                                    const int* __restrict__ rlist,
                                                    const int* __restrict__ ctr,
                                                    float* __restrict__ out,
                                                    int* __restrict__ labels) {
    int s = blockIdx.x * 256 + threadIdx.x;      // grid 16
    int n = min(*ctr, FCAP);
    if (s >= n) return;
    float b = 3.4e38f; int bi = 0x7fffffff;
    for (int c = 0; c < 16; c++) {
        float v = fbest[c * FCAP + s]; int ix = fidx[c * FCAP + s];
        if (v < b || (v == b && ix < bi)) { b = v; bi = ix; }
    }
    int row = rlist[s];
    out[row] = (float)bi;
    labels[row] = bi;
}

// ---------------- gather assigned centroids ---------------------------------
__global__ __launch_bounds__(256) void gather(const float* __restrict__ cen,
                                              const int* __restrict__ labels,
                                              float* __restrict__ out) {
    __shared__ int lab[8];
    const int tid = threadIdx.x;
    const int rowBase = blockIdx.x * 8;
    if (tid < 8) lab[tid] = labels[rowBase + tid];
    __syncthreads();
    float* assigned = out + BROWS;
    #pragma unroll 4
    for (int s = tid; s < 8 * 128; s += 256) {
        int r = s >> 7;
        int f = (s & 127) * 4;
        float4 v = *(const float4*)(cen + (size_t)lab[r] * DD + f);
        *(float4*)(assigned + (size_t)(rowBase + r) * DD + f) = v;
    }
}

extern "C" void kernel_launch(void* const* d_in, const int* in_sizes, int n_in,
                              void* d_out, int out_size, void* d_ws, size_t ws_size,
                              hipStream_t stream) {
    const float* x   = (const float*)d_in[0];
    const float* cen = (const float*)d_in[1];

    char* base = (char*)d_ws;
    _Float16* xh   = (_Float16*)(base);                    // 32 MB
    _Float16* ch   = (_Float16*)(base + 33554432);         // 2 MB
    float* csq     = (float*)(base + 35651584);            // 8 KB
    float* pbest   = (float*)(base + 35659776);            // 4 MB
    float* psec    = (float*)(base + 39854080);            // 4 MB
    int*   pidx    = (int*)  (base + 44048384);            // 4 MB
    int*   labels  = (int*)  (base + 48242688);            // 128 KB
    int*   rlist   = (int*)  (base + 48373760);            // 16 KB
    float* fbest   = (float*)(base + 48390144);            // 256 KB
    int*   fidx    = (int*)  (base + 48652288);            // 256 KB
    int*   ctr     = (int*)  (base + 48914432);            // 4 B

    prep<<<KC / 4 + BROWS * DD / 4 / 256, 256, 0, stream>>>(x, cen, xh, ch, csq, ctr);
    dist_f16<<<dim3(BROWS / 128, KC / 128), 256, 0, stream>>>(xh, ch, csq, pbest, psec, pidx);
    reduce_rows<<<BROWS / 256, 256, 0, stream>>>(pbest, psec, pidx, (float*)d_out, labels, rlist, ctr);
    fixup_dist<<<dim3(KC / 128, FCAP / 128), 256, 0, stream>>>(x, cen, csq, rlist, ctr, fbest, fidx);
    fixup_reduce<<<FCAP / 256, 256, 0, stream>>>(fbest, fidx, rlist, ctr, (float*)d_out, labels);
    gather<<<BROWS / 8, 256, 0, stream>>>(cen, labels, (float*)d_out);
}

// Round 10
// 272.123 us; speedup vs baseline: 1.1716x; 1.0083x over previous
//
#include <hip/hip_runtime.h>
#include <hip/hip_bf16.h>

// KMeans assign via fp16 coarse MFMA + fp16x2-limb MFMA fixup of near-ties.
// argmin_k ||xe - c_k|| == argmin_k ( ||c_k||^2 - 2*xe.c_k ),  xe = x + 1e-6.
// Rows with coarse top2 gap < TAU=0.3 are exactly rescored (fp32-equivalent).
//
// R8: single-variable round — XCD-locality swizzle for dist_f16's A panel.
// Old grid (x=row,y=col) put the 16 blocks sharing one 128KB xh row-slice
// 256 dispatch slots apart -> slice fetched up to 16x from L3/HBM (FETCH
// 102MB vs 34MB logical). New: 1D grid, r = xcd + 8*(t + 16*gq) with
// g = gq*8+xcd -> a row-group's 16 col-tiles land on ONE XCD (round-robin
// dispatch heuristic), slice lives in that XCD's L2. Everything else
// byte-identical to R7 (dist=R4 structure, 102.7-103.5us verified).
// Tail note: ~90-100us of the total is a fixed cost consistent across all
// rounds (likely harness reset dispatches), not addressable from kernels.
// SQ_LDS_BANK_CONFLICT = fixed DMA-write cost per global_load_lds
// (exact-count verified R1-R7: 8 cyc/instr @256thr).

#define EPS 1e-6f
#define TAU 0.3f

constexpr int BROWS = 32768;   // 8*4096 rows
constexpr int DD    = 512;
constexpr int KC    = 2048;    // centroids
constexpr int FCAP  = 4096;    // max flagged rows handled exactly
constexpr int NK    = DD / 32; // 16 K-steps

typedef _Float16 half8  __attribute__((ext_vector_type(8)));
typedef _Float16 half4v __attribute__((ext_vector_type(4)));
typedef float    f32x4  __attribute__((ext_vector_type(4)));

// ---------------- fused prep: x->fp16(+eps), centroids->fp16 + csq ----------
__global__ __launch_bounds__(256) void prep(const float* __restrict__ x,
                                            const float* __restrict__ cen,
                                            _Float16* __restrict__ xh,
                                            _Float16* __restrict__ ch,
                                            float* __restrict__ csq,
                                            int* __restrict__ ctr) {
    const int bid = blockIdx.x;
    if (bid < KC / 4) {
        // centroid block (grid 512 -> 2048 rows)
        if (bid == 0 && threadIdx.x == 0) *ctr = 0;
        int w = threadIdx.x >> 6, lane = threadIdx.x & 63;
        int c = bid * 4 + w;
        const float* row = cen + (size_t)c * DD;
        float4 v0 = *(const float4*)(row + lane * 8);
        float4 v1 = *(const float4*)(row + lane * 8 + 4);
        half8 h;
        h[0] = (_Float16)v0.x; h[1] = (_Float16)v0.y; h[2] = (_Float16)v0.z; h[3] = (_Float16)v0.w;
        h[4] = (_Float16)v1.x; h[5] = (_Float16)v1.y; h[6] = (_Float16)v1.z; h[7] = (_Float16)v1.w;
        *(half8*)(ch + (size_t)c * DD + lane * 8) = h;
        float s = v0.x*v0.x + v0.y*v0.y + v0.z*v0.z + v0.w*v0.w
                + v1.x*v1.x + v1.y*v1.y + v1.z*v1.z + v1.w*v1.w;
        #pragma unroll
        for (int off = 32; off > 0; off >>= 1) s += __shfl_down(s, off, 64);
        if (lane == 0) csq[c] = s;
    } else {
        size_t i = ((size_t)(bid - KC / 4) * 256 + threadIdx.x) * 4;
        float4 v = *(const float4*)(x + i);
        half4v h;
        h[0] = (_Float16)(v.x + EPS); h[1] = (_Float16)(v.y + EPS);
        h[2] = (_Float16)(v.z + EPS); h[3] = (_Float16)(v.w + EPS);
        *(half4v*)(xh + i) = h;
    }
}

// ---------------- coarse fp16 MFMA distance + per-row top2 ------------------
// 128x128 tile, 4 waves of 64x64. A 3-buf (stage k+2), B 2-buf (stage k+1),
// counted s_waitcnt vmcnt(2) + raw s_barrier per K-step. LDS 40KB.
// 1D grid 4096, XCD-locality decode: r = xcd + 8*(t + 16*gq), g = gq*8+xcd.
__global__ __launch_bounds__(256, 4) void dist_f16(const _Float16* __restrict__ xh,
                                                   const _Float16* __restrict__ ch,
                                                   const float* __restrict__ csq,
                                                   float* __restrict__ pbest,
                                                   float* __restrict__ psec,
                                                   int*   __restrict__ pidx) {
    // A tiles: smem + {0,1,2}*4096 halfs; B tiles: smem + 12288 + {0,1}*4096.
    __shared__ __align__(16) _Float16 smem[5 * 4096];     // 40 KB exactly

    const int tid = threadIdx.x;
    const int w = tid >> 6, lane = tid & 63;
    const int wr = w >> 1, wc = w & 1;
    const int quad = lane >> 4, u = lane & 15;

    // XCD-locality decode: row-group g's 16 col-tiles share one XCD.
    const int rblk = blockIdx.x;
    const int xcd = rblk & 7;
    const int q   = rblk >> 3;
    const int t   = q & 15;          // col tile 0..15
    const int gq  = q >> 4;          // 0..31
    const int g   = gq * 8 + xcd;    // row group 0..255
    const int rowBase = g * 128;
    const int colBase = t * 128;

    // csq loads pinned before the pipeline (cannot cross the asm fences).
    float cq[4];
    #pragma unroll
    for (int fc = 0; fc < 4; fc++) cq[fc] = csq[colBase + wc * 64 + fc * 16 + u];

    // Staging granules (16B each), g in [0,512): LDS row g>>2, slot g&3.
    const int g0 = 128 * w + lane;
    const int g1 = g0 + 64;
    const int r0 = g0 >> 2, h0 = g0 & 3;
    const int r1 = g1 >> 2, h1 = g1 & 3;
    const _Float16* pa0 = xh + (size_t)(rowBase + r0) * DD + h0 * 8;
    const _Float16* pa1 = xh + (size_t)(rowBase + r1) * DD + h1 * 8;
    const _Float16* pb0 = ch + (size_t)(colBase + r0) * DD + h0 * 8;
    const _Float16* pb1 = ch + (size_t)(colBase + r1) * DD + h1 * 8;

    auto stageA = [&](int kt) {   // 2 global_load_lds per thread
        _Float16* dst = smem + (kt % 3) * 4096;
        const int off = kt * 32;
        __builtin_amdgcn_global_load_lds(
            (const __attribute__((address_space(1))) void*)(pa0 + off),
            (__attribute__((address_space(3))) void*)(dst + g0 * 8), 16, 0, 0);
        __builtin_amdgcn_global_load_lds(
            (const __attribute__((address_space(1))) void*)(pa1 + off),
            (__attribute__((address_space(3))) void*)(dst + g1 * 8), 16, 0, 0);
    };
    auto stageB = [&](int kt) {   // 2 global_load_lds per thread
        _Float16* dst = smem + 12288 + (kt % 2) * 4096;
        const int off = kt * 32;
        __builtin_amdgcn_global_load_lds(
            (const __attribute__((address_space(1))) void*)(pb0 + off),
            (__attribute__((address_space(3))) void*)(dst + g0 * 8), 16, 0, 0);
        __builtin_amdgcn_global_load_lds(
            (const __attribute__((address_space(1))) void*)(pb1 + off),
            (__attribute__((address_space(3))) void*)(dst + g1 * 8), 16, 0, 0);
    };

    f32x4 acc[4][4] = {};

    // prologue: queue = [A0, B0, A1] (6 loads outstanding)
    stageA(0); stageB(0); stageA(1);

    #pragma unroll
    for (int kc = 0; kc < NK; kc++) {
        // wait for tiles A(kc), B(kc); leave A(kc+1)'s 2 loads in flight.
        if (kc + 1 < NK) asm volatile("s_waitcnt vmcnt(2)" ::: "memory");
        else             asm volatile("s_waitcnt vmcnt(0)" ::: "memory");
        __builtin_amdgcn_s_barrier();
        asm volatile("" ::: "memory");
        __builtin_amdgcn_sched_barrier(0);

        if (kc + 1 < NK) stageB(kc + 1);   // into bbuf[(kc+1)%2] (read kc-1, retired)
        if (kc + 2 < NK) stageA(kc + 2);   // into abuf[(kc+2)%3] (read kc-1, retired)

        const _Float16* abuf = smem + (kc % 3) * 4096;
        const _Float16* bbuf = smem + 12288 + (kc % 2) * 4096;
        half8 af[4], bf[4];
        #pragma unroll
        for (int f = 0; f < 4; f++) {
            af[f] = *(const half8*)(abuf + (wr * 64 + f * 16 + u) * 32 + quad * 8);
            bf[f] = *(const half8*)(bbuf + (wc * 64 + f * 16 + u) * 32 + quad * 8);
        }
        #pragma unroll
        for (int fr = 0; fr < 4; fr++)
            #pragma unroll
            for (int fc = 0; fc < 4; fc++)
                acc[fr][fc] = __builtin_amdgcn_mfma_f32_16x16x32_f16(af[fr], bf[fc], acc[fr][fc], 0, 0, 0);
    }

    __syncthreads();   // all LDS reads retired; safe to overlay epilogue staging

    // epilogue staging overlays the A-buffers (3 KB of 40 KB).
    float* ebf = (float*)smem;           // [4][64]
    float* esf = ebf + 256;              // [4][64]
    int*   eif = (int*)(esf + 256);      // [4][64]

    const int cbi = t * 2 + wc;
    const int colQuadBase = colBase + wc * 64;

    #pragma unroll
    for (int fr = 0; fr < 4; fr++) {
        #pragma unroll
        for (int reg = 0; reg < 4; reg++) {
            float vv[4];
            #pragma unroll
            for (int fc = 0; fc < 4; fc++) vv[fc] = cq[fc] - 2.0f * acc[fr][fc][reg];
            // top2 of 4 (min/max network); no coarse tie-break needed
            float mn01 = fminf(vv[0], vv[1]), mx01 = fmaxf(vv[0], vv[1]);
            float mn23 = fminf(vv[2], vv[3]), mx23 = fmaxf(vv[2], vv[3]);
            float b = fminf(mn01, mn23);
            float s = fminf(fmaxf(mn01, mn23), fminf(mx01, mx23));
            #pragma unroll
            for (int m = 1; m < 16; m <<= 1) {   // butterfly within quad
                float ob = __shfl_xor(b, m, 64);
                float os = __shfl_xor(s, m, 64);
                s = fminf(fminf(s, os), fmaxf(b, ob));
                b = fminf(b, ob);
            }
            int bi = 0x7fffffff;
            #pragma unroll
            for (int fc = 0; fc < 4; fc++) {
                unsigned long long mm = __ballot(vv[fc] == b);
                unsigned q16 = (unsigned)((mm >> (quad * 16)) & 0xFFFFu);
                if (bi == 0x7fffffff && q16)
                    bi = colQuadBase + fc * 16 + (__ffs(q16) - 1);
            }
            if (u == 0) {
                int rl = fr * 16 + quad * 4 + reg;   // local row 0..63
                ebf[w * 64 + rl] = b; esf[w * 64 + rl] = s; eif[w * 64 + rl] = bi;
            }
        }
    }
    __syncthreads();
    // coalesced partial stores: 64 contiguous rows per wave per array
    {
        const int base = cbi * BROWS + rowBase + wr * 64;
        pbest[base + lane] = ebf[w * 64 + lane];
        psec [base + lane] = esf[w * 64 + lane];
        pidx [base + lane] = eif[w * 64 + lane];
    }
}

// ---------------- merge 32 partials per row; flag near-ties -----------------
__global__ __launch_bounds__(256) void reduce_rows(const float* __restrict__ pbest,
                                                   const float* __restrict__ psec,
                                                   const int* __restrict__ pidx,
                                                   float* __restrict__ out,
                                                   int* __restrict__ labels,
                                                   int* __restrict__ rlist,
                                                   int* __restrict__ ctr) {
    int row = blockIdx.x * 256 + threadIdx.x;    // grid 128
    float b = 3.4e38f, s = 3.4e38f; int bi = 0x7fffffff;
    for (int p = 0; p < 32; p++) {
        float v  = pbest[p * BROWS + row];
        float sv = psec [p * BROWS + row];
        int   vi = pidx [p * BROWS + row];
        if (v < b) { s = fminf(b, fminf(s, sv)); b = v; bi = vi; }
        else       { s = fminf(s, fminf(v, sv)); }
    }
    out[row] = (float)bi;
    labels[row] = bi;
    if (s - b < TAU) {
        int slot = atomicAdd(ctr, 1);
        if (slot < FCAP) rlist[slot] = row;
    }
}

// ---------------- fp16x2-limb MFMA rescore of flagged rows ------------------
// 128x128 tile, 4 waves of 64x64. Stages raw fp32 x/cen (global_load_lds,
// XOR slot swizzle), splits to fp16 hi/lo limbs in-register, accumulates
// hh+hl+lh into one fp32 acc (48 MFMA/step/wave). ll dropped (~5e-7 abs).
__global__ __launch_bounds__(256, 2) void fixup_dist(const float* __restrict__ x,
                                                     const float* __restrict__ cen,
                                                     const float* __restrict__ csq,
                                                     const int* __restrict__ rlist,
                                                     const int* __restrict__ ctr,
                                                     float* __restrict__ fbest,
                                                     int*   __restrict__ fidx) {
    int n = min(*ctr, FCAP);
    int tilebase = blockIdx.y * 128;
    if (tilebase >= n) return;

    __shared__ __align__(16) float asmem[2][128 * 32];   // 32 KB
    __shared__ __align__(16) float bsmem[2][128 * 32];   // 32 KB
    __shared__ int   rows_s[128];
    __shared__ float fb[2][128];
    __shared__ int   fi[2][128];

    const int tid = threadIdx.x;
    if (tid < 128) {
        int ii = tilebase + tid;
        rows_s[tid] = (ii < n) ? rlist[ii] : rlist[0];   // clamp (dup row 0's entry)
    }
    __syncthreads();

    const int w = tid >> 6, lane = tid & 63;
    const int wr = w >> 1, wc = w & 1;
    const int quad = lane >> 4, u = lane & 15;
    const int colBase = blockIdx.x * 128;

    // Staging granules (16B = 4 floats), g in [0,1024): row g>>3, slot g&7.
    // Both-sides XOR swizzle: source chunk = slot ^ (row&7); read applies same.
    const float* pa[4]; const float* pb[4]; int ldsg[4];
    #pragma unroll
    for (int j = 0; j < 4; j++) {
        int g = j * 256 + tid;         // = j*256 + w*64 + lane (lane-contiguous)
        int r = g >> 3, s = (g & 7) ^ (r & 7);
        pa[j] = x   + (size_t)rows_s[r] * DD + s * 4;
        pb[j] = cen + (size_t)(colBase + r) * DD + s * 4;
        ldsg[j] = g * 4;               // float offset (16B granule)
    }

    auto stage = [&](int kt) {   // 8 global_load_lds per thread
        float* da = asmem[kt & 1];
        float* db = bsmem[kt & 1];
        const int off = kt * 32;
        #pragma unroll
        for (int j = 0; j < 4; j++) {
            __builtin_amdgcn_global_load_lds(
                (const __attribute__((address_space(1))) void*)(pa[j] + off),
                (__attribute__((address_space(3))) void*)(da + ldsg[j]), 16, 0, 0);
            __builtin_amdgcn_global_load_lds(
                (const __attribute__((address_space(1))) void*)(pb[j] + off),
                (__attribute__((address_space(3))) void*)(db + ldsg[j]), 16, 0, 0);
        }
    };

    f32x4 acc[4][4] = {};
    stage(0);

    for (int kc = 0; kc < NK; kc++) {
        asm volatile("s_waitcnt vmcnt(0)" ::: "memory");
        __builtin_amdgcn_s_barrier();
        asm volatile("" ::: "memory");
        __builtin_amdgcn_sched_barrier(0);
        if (kc + 1 < NK) stage(kc + 1);

        const float* ab = asmem[kc & 1];
        const float* bb = bsmem[kc & 1];
        half8 aH[4], aL[4], bH[4], bL[4];
        #pragma unroll
        for (int f = 0; f < 4; f++) {
            {   // A frag: rows of x (add EPS), k-chunk quad*8..+7
                const float* base = ab + (wr * 64 + f * 16 + u) * 32;
                int s0 = ((quad << 1) | 0) ^ (u & 7);
                int s1 = ((quad << 1) | 1) ^ (u & 7);
                float4 v0 = *(const float4*)(base + s0 * 4);
                float4 v1 = *(const float4*)(base + s1 * 4);
                float fs[8] = {v0.x, v0.y, v0.z, v0.w, v1.x, v1.y, v1.z, v1.w};
                #pragma unroll
                for (int e = 0; e < 8; e++) {
                    float fe = fs[e] + EPS;
                    _Float16 hi = (_Float16)fe;
                    aH[f][e] = hi;
                    aL[f][e] = (_Float16)(fe - (float)hi);
                }
            }
            {   // B frag: rows of cen (no EPS)
                const float* base = bb + (wc * 64 + f * 16 + u) * 32;
                int s0 = ((quad << 1) | 0) ^ (u & 7);
                int s1 = ((quad << 1) | 1) ^ (u & 7);
                float4 v0 = *(const float4*)(base + s0 * 4);
                float4 v1 = *(const float4*)(base + s1 * 4);
                float fs[8] = {v0.x, v0.y, v0.z, v0.w, v1.x, v1.y, v1.z, v1.w};
                #pragma unroll
                for (int e = 0; e < 8; e++) {
                    float fe = fs[e];
                    _Float16 hi = (_Float16)fe;
                    bH[f][e] = hi;
                    bL[f][e] = (_Float16)(fe - (float)hi);
                }
            }
        }
        #pragma unroll
        for (int fr = 0; fr < 4; fr++)
            #pragma unroll
            for (int fc = 0; fc < 4; fc++) {
                acc[fr][fc] = __builtin_amdgcn_mfma_f32_16x16x32_f16(aH[fr], bL[fc], acc[fr][fc], 0, 0, 0);
                acc[fr][fc] = __builtin_amdgcn_mfma_f32_16x16x32_f16(aL[fr], bH[fc], acc[fr][fc], 0, 0, 0);
                acc[fr][fc] = __builtin_amdgcn_mfma_f32_16x16x32_f16(aH[fr], bH[fc], acc[fr][fc], 0, 0, 0);
            }
    }

    // per-row argmin with index tie-break (final authority)
    float cqv[4];
    #pragma unroll
    for (int fc = 0; fc < 4; fc++) cqv[fc] = csq[colBase + wc * 64 + fc * 16 + u];
    const int colQuadBase = colBase + wc * 64;

    #pragma unroll
    for (int fr = 0; fr < 4; fr++) {
        #pragma unroll
        for (int reg = 0; reg < 4; reg++) {
            float b = 3.4e38f; int bi = 0x7fffffff;
            #pragma unroll
            for (int fc = 0; fc < 4; fc++) {
                float v = cqv[fc] - 2.0f * acc[fr][fc][reg];
                int c = colQuadBase + fc * 16 + u;
                if (v < b || (v == b && c < bi)) { b = v; bi = c; }
            }
            #pragma unroll
            for (int m = 1; m < 16; m <<= 1) {   // butterfly within quad
                float ob = __shfl_xor(b, m, 64);
                int  obi = __shfl_xor(bi, m, 64);
                if (ob < b || (ob == b && obi < bi)) { b = ob; bi = obi; }
            }
            if (u == 0) {
                int rl = wr * 64 + fr * 16 + quad * 4 + reg;   // local row 0..127
                fb[wc][rl] = b; fi[wc][rl] = bi;
            }
        }
    }
    __syncthreads();
    if (tid < 128) {
        float b0 = fb[0][tid]; int i0 = fi[0][tid];
        float b1 = fb[1][tid]; int i1 = fi[1][tid];
        float b; int bi;
        if (b1 < b0 || (b1 == b0 && i1 < i0)) { b = b1; bi = i1; }
        else                                  { b = b0; bi = i0; }
        fbest[blockIdx.x * FCAP + tilebase + tid] = b;
        fidx [blockIdx.x * FCAP + tilebase + tid] = bi;
    }
}

__global__ __launch_bounds__(256) void fixup_reduce(const float* __restrict__ fbest,
                                                    const int* __restrict__ fidx,
                                                    const int* __restrict__ rlist,
                                                    const int* __restrict__ ctr,
                                                    float* __restrict__ out,
                                                    int* __restrict__ labels) {
    int s = blockIdx.x * 256 + threadIdx.x;      // grid 16
    int n = min(*ctr, FCAP);
    if (s >= n) return;
    float b = 3.4e38f; int bi = 0x7fffffff;
    for (int c = 0; c < 16; c++) {
        float v = fbest[c * FCAP + s]; int ix = fidx[c * FCAP + s];
        if (v < b || (v == b && ix < bi)) { b = v; bi = ix; }
    }
    int row = rlist[s];
    out[row] = (float)bi;
    labels[row] = bi;
}

// ---------------- gather assigned centroids ---------------------------------
__global__ __launch_bounds__(256) void gather(const float* __restrict__ cen,
                                              const int* __restrict__ labels,
                                              float* __restrict__ out) {
    __shared__ int lab[8];
    const int tid = threadIdx.x;
    const int rowBase = blockIdx.x * 8;
    if (tid < 8) lab[tid] = labels[rowBase + tid];
    __syncthreads();
    float* assigned = out + BROWS;
    #pragma unroll 4
    for (int s = tid; s < 8 * 128; s += 256) {
        int r = s >> 7;
        int f = (s & 127) * 4;
        float4 v = *(const float4*)(cen + (size_t)lab[r] * DD + f);
        *(float4*)(assigned + (size_t)(rowBase + r) * DD + f) = v;
    }
}

extern "C" void kernel_launch(void* const* d_in, const int* in_sizes, int n_in,
                              void* d_out, int out_size, void* d_ws, size_t ws_size,
                              hipStream_t stream) {
    const float* x   = (const float*)d_in[0];
    const float* cen = (const float*)d_in[1];

    char* base = (char*)d_ws;
    _Float16* xh   = (_Float16*)(base);                    // 32 MB
    _Float16* ch   = (_Float16*)(base + 33554432);         // 2 MB
    float* csq     = (float*)(base + 35651584);            // 8 KB
    float* pbest   = (float*)(base + 35659776);            // 4 MB
    float* psec    = (float*)(base + 39854080);            // 4 MB
    int*   pidx    = (int*)  (base + 44048384);            // 4 MB
    int*   labels  = (int*)  (base + 48242688);            // 128 KB
    int*   rlist   = (int*)  (base + 48373760);            // 16 KB
    float* fbest   = (float*)(base + 48390144);            // 256 KB
    int*   fidx    = (int*)  (base + 48652288);            // 256 KB
    int*   ctr     = (int*)  (base + 48914432);            // 4 B

    prep<<<KC / 4 + BROWS * DD / 4 / 256, 256, 0, stream>>>(x, cen, xh, ch, csq, ctr);
    dist_f16<<<(BROWS / 128) * (KC / 128), 256, 0, stream>>>(xh, ch, csq, pbest, psec, pidx);
    reduce_rows<<<BROWS / 256, 256, 0, stream>>>(pbest, psec, pidx, (float*)d_out, labels, rlist, ctr);
    fixup_dist<<<dim3(KC / 128, FCAP / 128), 256, 0, stream>>>(x, cen, csq, rlist, ctr, fbest, fidx);
    fixup_reduce<<<FCAP / 256, 256, 0, stream>>>(fbest, fidx, rlist, ctr, (float*)d_out, labels);
    gather<<<BROWS / 8, 256, 0, stream>>>(cen, labels, (float*)d_out);
}